// Round 1
// baseline (12757.279 us; speedup 1.0000x reference)
//
#include <hip/hip_runtime.h>
#include <hip/hip_bf16.h>

// Problem dims (fixed)
#define BB 64
#define NN 50
#define TT 30
#define EE 300
#define FN 400
#define AA 200
#define GG 400

// ---------------------------------------------------------------------------
// K0: transpose W [1200][400] -> WT [400][1200] (one-time, ~2MB each)
// ---------------------------------------------------------------------------
__global__ void k_transpose(const float* __restrict__ in, float* __restrict__ out) {
  int idx = blockIdx.x * 256 + threadIdx.x;
  if (idx < 1200 * 400) {
    int j = idx / 400, f = idx % 400;
    out[f * 1200 + j] = in[idx];   // read coalesced, write strided (tiny, one-time)
  }
}

// ---------------------------------------------------------------------------
// K1: fused embedding gather + conv1d(K=3,pad=1) + ReLU + attention scores.
// One block per (b,n) title. 448 threads (7 waves).
// LDS union buffer: phase1 embT[300][36] (43.2KB) -> phase2 C_lds[400][36]
// (57.6KB) -> phase3 wq stage[30][225]. 2 blocks/CU by LDS.
// ---------------------------------------------------------------------------
__global__ __launch_bounds__(448, 4) void k1_conv_attn(
    const int* __restrict__ title,       // [B*N*T]
    const float* __restrict__ word_emb,  // [VOCAB*E]
    const float* __restrict__ conv_w,    // [K*E*FN]  (k,e,f)
    const float* __restrict__ conv_b,    // [FN]
    const float* __restrict__ v,         // [FN*A]
    const float* __restrict__ vb,        // [A]
    const float* __restrict__ q,         // [A]
    __hip_bfloat16* __restrict__ Cout,   // [B*N*T*FN]
    float* __restrict__ score)           // [B*N*T]
{
  __shared__ float smem[FN * 36];  // 57.6 KB union buffer
  __shared__ int words[TT];
  const int bn = blockIdx.x;
  const int tid = threadIdx.x;

  if (tid < TT) words[tid] = title[bn * TT + tid];
  __syncthreads();

  // ---- phase 1: gather word embeddings, transposed: embT[e][slot], slot=t+1
  // slot 0 and 31 are the zero conv padding.
  for (int idx = tid; idx < 2 * EE; idx += 448) {
    int e = idx >> 1;
    int s = (idx & 1) ? 31 : 0;
    smem[e * 36 + s] = 0.f;
  }
  for (int idx = tid; idx < TT * EE; idx += 448) {
    int t = idx / EE, e = idx - t * EE;  // consecutive lanes -> consecutive e (coalesced read)
    smem[e * 36 + (t + 1)] = word_emb[(long)words[t] * EE + e];
  }
  __syncthreads();

  // ---- phase 2: conv. thread = output channel f (tid < 400). acc over all 30 t.
  float acc[TT];
  if (tid < FN) {
    float cb = conv_b[tid];
#pragma unroll
    for (int t = 0; t < TT; ++t) acc[t] = cb;
    for (int e = 0; e < EE; ++e) {
      float em[32];
      const float* col = &smem[e * 36];
#pragma unroll
      for (int r = 0; r < 8; ++r)
        *(float4*)(&em[r * 4]) = *(const float4*)(col + r * 4);  // LDS broadcast
#pragma unroll
      for (int k = 0; k < 3; ++k) {
        float w = conv_w[(k * EE + e) * FN + tid];  // coalesced across f, L2-hot
#pragma unroll
        for (int t = 0; t < TT; ++t) acc[t] = fmaf(em[t + k], w, acc[t]);
      }
    }
#pragma unroll
    for (int t = 0; t < TT; ++t) acc[t] = fmaxf(acc[t], 0.f);  // ReLU
    // global C store (bf16), coalesced across f
#pragma unroll
    for (int t = 0; t < TT; ++t)
      Cout[(bn * TT + t) * FN + tid] = __float2bfloat16(acc[t]);
  }
  __syncthreads();  // embT dead

  // write C into LDS transposed: C_lds[f][t] (slots 30,31 zeroed for b128 reads)
  if (tid < FN) {
#pragma unroll
    for (int t = 0; t < TT; ++t) smem[tid * 36 + t] = acc[t];
    smem[tid * 36 + 30] = 0.f;
    smem[tid * 36 + 31] = 0.f;
  }
  __syncthreads();

  // ---- phase 3: attention pre-activation ap[t][a] = sum_f C[t,f] v[f,a]
  // thread -> (a = tid%224, half = tid/224 covering t in [half*16, +16))
  const int a = tid % 224;
  const int half = tid / 224;
  const int t0 = half * 16;
  float ap[16];
#pragma unroll
  for (int i = 0; i < 16; ++i) ap[i] = 0.f;
  if (a < AA) {
    for (int f = 0; f < FN; ++f) {
      float vw = v[f * AA + a];  // coalesced across a
      float cv[16];
      const float* crow = &smem[f * 36 + t0];
#pragma unroll
      for (int r = 0; r < 4; ++r)
        *(float4*)(&cv[r * 4]) = *(const float4*)(crow + r * 4);
#pragma unroll
      for (int i = 0; i < 16; ++i) ap[i] = fmaf(cv[i], vw, ap[i]);
    }
  }
  __syncthreads();  // C_lds dead; reuse smem as stage[30][225]

  if (a < AA) {
    float qa = q[a];
    float vba = vb[a];
#pragma unroll
    for (int i = 0; i < 16; ++i) {
      int t = t0 + i;
      if (t < TT) smem[t * 225 + a] = tanhf(ap[i] + vba) * qa;
    }
  }
  __syncthreads();

  if (tid < TT) {
    float s = 0.f;
    for (int a2 = 0; a2 < AA; ++a2) s += smem[tid * 225 + a2];  // stride 225: conflict-free
    score[bn * TT + tid] = s;
  }
}

// ---------------------------------------------------------------------------
// K2: softmax over the N (titles) axis, per (b,t). 1920 independent rows of 50.
// ---------------------------------------------------------------------------
__global__ void k2_softmax_n(const float* __restrict__ score, float* __restrict__ alpha) {
  int i = blockIdx.x * 256 + threadIdx.x;
  if (i >= BB * TT) return;
  int b = i / TT, t = i - b * TT;
  int base = b * (NN * TT) + t;
  float m = -1e30f;
  for (int n = 0; n < NN; ++n) m = fmaxf(m, score[base + n * TT]);
  float s = 0.f;
  for (int n = 0; n < NN; ++n) s += __expf(score[base + n * TT] - m);
  float inv = 1.f / s;
  for (int n = 0; n < NN; ++n)
    alpha[base + n * TT] = __expf(score[base + n * TT] - m) * inv;
}

// ---------------------------------------------------------------------------
// K3: weighted sum over words: e[bn,f] = sum_t alpha[bn,t] * C[bn,t,f]
// ---------------------------------------------------------------------------
__global__ __launch_bounds__(256) void k3_wsum(
    const float* __restrict__ alpha, const __hip_bfloat16* __restrict__ C,
    float* __restrict__ eout) {
  __shared__ float al[TT];
  const int bn = blockIdx.x;
  const int tid = threadIdx.x;
  if (tid < TT) al[tid] = alpha[bn * TT + tid];
  __syncthreads();
  for (int f = tid; f < FN; f += 256) {
    float s = 0.f;
#pragma unroll
    for (int t = 0; t < TT; ++t)
      s = fmaf(al[t], __bfloat162float(C[(bn * TT + t) * FN + f]), s);
    eout[bn * FN + f] = s;
  }
}

// ---------------------------------------------------------------------------
// K4: gx = e @ W_ih^T + b_ih   (3200x400 @ 400x1200). 16 rows per block.
// ---------------------------------------------------------------------------
__global__ __launch_bounds__(256) void k4_gx(
    const float* __restrict__ e, const float* __restrict__ WihT,  // [400][1200]
    const float* __restrict__ b_ih, float* __restrict__ gx) {
  __shared__ float elds[FN * 16];  // [f][r], 25.6KB
  const int row0 = blockIdx.x * 16;
  const int tid = threadIdx.x;
  for (int idx = tid; idx < FN * 16; idx += 256) {
    int r = idx / FN, f = idx - r * FN;
    elds[f * 16 + r] = e[(row0 + r) * FN + f];
  }
  __syncthreads();
#pragma unroll
  for (int jc = 0; jc < 5; ++jc) {
    int j = tid + jc * 256;
    if (j >= 1200) break;
    float bj = b_ih[j];
    float acc[16];
#pragma unroll
    for (int r = 0; r < 16; ++r) acc[r] = bj;
    for (int f = 0; f < FN; ++f) {
      float w = WihT[f * 1200 + j];  // coalesced across j
      float ev[16];
      const float* ep = &elds[f * 16];
#pragma unroll
      for (int r = 0; r < 4; ++r)
        *(float4*)(&ev[r * 4]) = *(const float4*)(ep + r * 4);
#pragma unroll
      for (int r = 0; r < 16; ++r) acc[r] = fmaf(ev[r], w, acc[r]);
    }
#pragma unroll
    for (int r = 0; r < 16; ++r) gx[(row0 + r) * 1200 + j] = acc[r];
  }
}

// ---------------------------------------------------------------------------
// K5: GRU, one block per batch element. h in LDS, 50 sequential steps.
// ---------------------------------------------------------------------------
__global__ __launch_bounds__(256) void k5_gru(
    const int* __restrict__ user_id, const int* __restrict__ hist_len,
    const float* __restrict__ user_emb, const float* __restrict__ WhhT,  // [400][1200]
    const float* __restrict__ b_hh, const float* __restrict__ gx,
    float* __restrict__ out) {
  __shared__ float h[GG];
  __shared__ float gh[1200];
  const int b = blockIdx.x;
  const int tid = threadIdx.x;
  const int uid = user_id[b];
  const int len = hist_len[b];
  for (int g = tid; g < GG; g += 256) h[g] = user_emb[(long)uid * GG + g];
  __syncthreads();

  for (int step = 0; step < NN; ++step) {
    // gh = h @ W_hh^T + b_hh
    float acc[5];
#pragma unroll
    for (int jc = 0; jc < 5; ++jc) {
      int j = tid + jc * 256;
      acc[jc] = (j < 1200) ? b_hh[j] : 0.f;
    }
    for (int g4 = 0; g4 < GG / 4; ++g4) {
      float4 hv = *(const float4*)(&h[g4 * 4]);  // LDS broadcast
#pragma unroll
      for (int c = 0; c < 4; ++c) {
        const float* Wr = WhhT + (g4 * 4 + c) * 1200;
        float hc = (c == 0) ? hv.x : (c == 1) ? hv.y : (c == 2) ? hv.z : hv.w;
#pragma unroll
        for (int jc = 0; jc < 5; ++jc) {
          int j = tid + jc * 256;
          if (j < 1200) acc[jc] = fmaf(Wr[j], hc, acc[jc]);
        }
      }
    }
#pragma unroll
    for (int jc = 0; jc < 5; ++jc) {
      int j = tid + jc * 256;
      if (j < 1200) gh[j] = acc[jc];
    }
    __syncthreads();

    const float* gxp = gx + (b * NN + step) * 1200;
    bool upd = step < len;
#pragma unroll
    for (int gc = 0; gc < 2; ++gc) {
      int g = tid + gc * 256;
      if (g < GG) {
        float xr = gxp[g], xz = gxp[400 + g], xn = gxp[800 + g];
        float hr = gh[g], hz = gh[400 + g], hn = gh[800 + g];
        float r = 1.f / (1.f + __expf(-(xr + hr)));
        float z = 1.f / (1.f + __expf(-(xz + hz)));
        float nn = tanhf(xn + r * hn);
        float hnew = (1.f - z) * nn + z * h[g];
        if (upd) h[g] = hnew;
      }
    }
    __syncthreads();
  }
  for (int g = tid; g < GG; g += 256) out[b * GG + g] = h[g];
}

// ---------------------------------------------------------------------------
extern "C" void kernel_launch(void* const* d_in, const int* in_sizes, int n_in,
                              void* d_out, int out_size, void* d_ws, size_t ws_size,
                              hipStream_t stream) {
  const int*   user_id   = (const int*)d_in[0];
  const int*   title     = (const int*)d_in[1];
  const int*   hist_len  = (const int*)d_in[2];
  const float* word_emb  = (const float*)d_in[3];
  const float* conv_w    = (const float*)d_in[4];
  const float* conv_b    = (const float*)d_in[5];
  const float* v         = (const float*)d_in[6];
  const float* vb        = (const float*)d_in[7];
  const float* q         = (const float*)d_in[8];
  const float* user_emb  = (const float*)d_in[9];
  const float* W_ih      = (const float*)d_in[10];
  const float* W_hh      = (const float*)d_in[11];
  const float* b_ih      = (const float*)d_in[12];
  const float* b_hh      = (const float*)d_in[13];
  float* out = (float*)d_out;

  // workspace layout (256B aligned)
  char* ws = (char*)d_ws;
  size_t off = 0;
  auto take = [&](size_t bytes) {
    char* p = ws + off;
    off = (off + bytes + 255) & ~(size_t)255;
    return p;
  };
  __hip_bfloat16* C  = (__hip_bfloat16*)take((size_t)BB * NN * TT * FN * 2);  // 76.8MB
  float* score  = (float*)take((size_t)BB * NN * TT * 4);
  float* alpha  = (float*)take((size_t)BB * NN * TT * 4);
  float* e      = (float*)take((size_t)BB * NN * FN * 4);
  float* WihT   = (float*)take((size_t)1200 * 400 * 4);
  float* WhhT   = (float*)take((size_t)1200 * 400 * 4);
  float* gx     = (float*)take((size_t)BB * NN * 1200 * 4);
  (void)ws_size;

  k_transpose<<<(1200 * 400 + 255) / 256, 256, 0, stream>>>(W_ih, WihT);
  k_transpose<<<(1200 * 400 + 255) / 256, 256, 0, stream>>>(W_hh, WhhT);
  k1_conv_attn<<<BB * NN, 448, 0, stream>>>(title, word_emb, conv_w, conv_b, v,
                                            vb, q, C, score);
  k2_softmax_n<<<(BB * TT + 255) / 256, 256, 0, stream>>>(score, alpha);
  k3_wsum<<<BB * NN, 256, 0, stream>>>(alpha, C, e);
  k4_gx<<<BB * NN / 16, 256, 0, stream>>>(e, WihT, b_ih, gx);
  k5_gru<<<BB, 256, 0, stream>>>(user_id, hist_len, user_emb, WhhT, b_hh, gx, out);
}

// Round 2
// 2409.366 us; speedup vs baseline: 5.2949x; 5.2949x over previous
//
#include <hip/hip_runtime.h>
#include <hip/hip_bf16.h>

// Problem dims (fixed)
#define BB 64
#define NN 50
#define TT 30
#define EE 300
#define FN 400
#define AA 200
#define GG 400

// ---------------------------------------------------------------------------
// K0: transpose W [1200][400] -> WT [400][1200] (one-time, ~2MB)
// ---------------------------------------------------------------------------
__global__ void k_transpose(const float* __restrict__ in, float* __restrict__ out) {
  int idx = blockIdx.x * 256 + threadIdx.x;
  if (idx < 1200 * 400) {
    int j = idx / 400, f = idx % 400;
    out[f * 1200 + j] = in[idx];
  }
}

// ---------------------------------------------------------------------------
// K0b: pack W_hh [1200 j][400 g] into Wpack[gc][g][150 jl]:
// for g-chunk gc (50 g's), the 150 columns {gate*400 + gc*50 + gl} contiguous.
// ---------------------------------------------------------------------------
__global__ void k_pack_whh(const float* __restrict__ Whh, float* __restrict__ Wpack) {
  int idx = blockIdx.x * 256 + threadIdx.x;
  if (idx < 8 * 400 * 150) {
    int jl = idx % 150;
    int g = (idx / 150) % 400;
    int gc = idx / (150 * 400);
    int gate = jl / 50, gl = jl - gate * 50;
    int j = gate * 400 + gc * 50 + gl;
    Wpack[idx] = Whh[j * 400 + g];
  }
}

// ---------------------------------------------------------------------------
// K1: fused embedding gather + conv1d(K=3,pad=1) + ReLU + attention scores.
// One block per (b,n) title. 448 threads (7 waves).
// ---------------------------------------------------------------------------
__global__ __launch_bounds__(448, 4) void k1_conv_attn(
    const int* __restrict__ title,       // [B*N*T]
    const float* __restrict__ word_emb,  // [VOCAB*E]
    const float* __restrict__ conv_w,    // [K*E*FN]  (k,e,f)
    const float* __restrict__ conv_b,    // [FN]
    const float* __restrict__ v,         // [FN*A]
    const float* __restrict__ vb,        // [A]
    const float* __restrict__ q,         // [A]
    __hip_bfloat16* __restrict__ Cout,   // [B*N*T*FN]
    float* __restrict__ score)           // [B*N*T]
{
  __shared__ float smem[FN * 36];  // 57.6 KB union buffer
  __shared__ int words[TT];
  const int bn = blockIdx.x;
  const int tid = threadIdx.x;

  if (tid < TT) words[tid] = title[bn * TT + tid];
  __syncthreads();

  // ---- phase 1: gather word embeddings, transposed: embT[e][slot], slot=t+1
  for (int idx = tid; idx < 2 * EE; idx += 448) {
    int e = idx >> 1;
    int s = (idx & 1) ? 31 : 0;
    smem[e * 36 + s] = 0.f;
  }
  for (int idx = tid; idx < TT * EE; idx += 448) {
    int t = idx / EE, e = idx - t * EE;
    smem[e * 36 + (t + 1)] = word_emb[(long)words[t] * EE + e];
  }
  __syncthreads();

  // ---- phase 2: conv. thread = output channel f (tid < 400).
  float acc[TT];
  if (tid < FN) {
    float cb = conv_b[tid];
#pragma unroll
    for (int t = 0; t < TT; ++t) acc[t] = cb;
    for (int e = 0; e < EE; ++e) {
      float em[32];
      const float* col = &smem[e * 36];
#pragma unroll
      for (int r = 0; r < 8; ++r)
        *(float4*)(&em[r * 4]) = *(const float4*)(col + r * 4);
#pragma unroll
      for (int k = 0; k < 3; ++k) {
        float w = conv_w[(k * EE + e) * FN + tid];
#pragma unroll
        for (int t = 0; t < TT; ++t) acc[t] = fmaf(em[t + k], w, acc[t]);
      }
    }
#pragma unroll
    for (int t = 0; t < TT; ++t) acc[t] = fmaxf(acc[t], 0.f);
#pragma unroll
    for (int t = 0; t < TT; ++t)
      Cout[(bn * TT + t) * FN + tid] = __float2bfloat16(acc[t]);
  }
  __syncthreads();

  if (tid < FN) {
#pragma unroll
    for (int t = 0; t < TT; ++t) smem[tid * 36 + t] = acc[t];
    smem[tid * 36 + 30] = 0.f;
    smem[tid * 36 + 31] = 0.f;
  }
  __syncthreads();

  // ---- phase 3: attention pre-activation ap[t][a] = sum_f C[t,f] v[f,a]
  const int a = tid % 224;
  const int half = tid / 224;
  const int t0 = half * 16;
  float ap[16];
#pragma unroll
  for (int i = 0; i < 16; ++i) ap[i] = 0.f;
  if (a < AA) {
    for (int f = 0; f < FN; ++f) {
      float vw = v[f * AA + a];
      float cv[16];
      const float* crow = &smem[f * 36 + t0];
#pragma unroll
      for (int r = 0; r < 4; ++r)
        *(float4*)(&cv[r * 4]) = *(const float4*)(crow + r * 4);
#pragma unroll
      for (int i = 0; i < 16; ++i) ap[i] = fmaf(cv[i], vw, ap[i]);
    }
  }
  __syncthreads();

  if (a < AA) {
    float qa = q[a];
    float vba = vb[a];
#pragma unroll
    for (int i = 0; i < 16; ++i) {
      int t = t0 + i;
      if (t < TT) smem[t * 225 + a] = tanhf(ap[i] + vba) * qa;
    }
  }
  __syncthreads();

  if (tid < TT) {
    float s = 0.f;
    for (int a2 = 0; a2 < AA; ++a2) s += smem[tid * 225 + a2];
    score[bn * TT + tid] = s;
  }
}

// ---------------------------------------------------------------------------
// K2: softmax over the N (titles) axis, per (b,t).
// ---------------------------------------------------------------------------
__global__ void k2_softmax_n(const float* __restrict__ score, float* __restrict__ alpha) {
  int i = blockIdx.x * 256 + threadIdx.x;
  if (i >= BB * TT) return;
  int b = i / TT, t = i - b * TT;
  int base = b * (NN * TT) + t;
  float m = -1e30f;
  for (int n = 0; n < NN; ++n) m = fmaxf(m, score[base + n * TT]);
  float s = 0.f;
  for (int n = 0; n < NN; ++n) s += __expf(score[base + n * TT] - m);
  float inv = 1.f / s;
  for (int n = 0; n < NN; ++n)
    alpha[base + n * TT] = __expf(score[base + n * TT] - m) * inv;
}

// ---------------------------------------------------------------------------
// K3: weighted sum over words: e[bn,f] = sum_t alpha[bn,t] * C[bn,t,f]
// ---------------------------------------------------------------------------
__global__ __launch_bounds__(256) void k3_wsum(
    const float* __restrict__ alpha, const __hip_bfloat16* __restrict__ C,
    float* __restrict__ eout) {
  __shared__ float al[TT];
  const int bn = blockIdx.x;
  const int tid = threadIdx.x;
  if (tid < TT) al[tid] = alpha[bn * TT + tid];
  __syncthreads();
  for (int f = tid; f < FN; f += 256) {
    float s = 0.f;
#pragma unroll
    for (int t = 0; t < TT; ++t)
      s = fmaf(al[t], __bfloat162float(C[(bn * TT + t) * FN + f]), s);
    eout[bn * FN + f] = s;
  }
}

// ---------------------------------------------------------------------------
// K4: gx = e @ W_ih^T + b_ih   (3200x400 @ 400x1200). 16 rows per block.
// ---------------------------------------------------------------------------
__global__ __launch_bounds__(256) void k4_gx(
    const float* __restrict__ e, const float* __restrict__ WihT,  // [400][1200]
    const float* __restrict__ b_ih, float* __restrict__ gx) {
  __shared__ float elds[FN * 16];
  const int row0 = blockIdx.x * 16;
  const int tid = threadIdx.x;
  for (int idx = tid; idx < FN * 16; idx += 256) {
    int r = idx / FN, f = idx - r * FN;
    elds[f * 16 + r] = e[(row0 + r) * FN + f];
  }
  __syncthreads();
#pragma unroll
  for (int jc = 0; jc < 5; ++jc) {
    int j = tid + jc * 256;
    if (j >= 1200) break;
    float bj = b_ih[j];
    float acc[16];
#pragma unroll
    for (int r = 0; r < 16; ++r) acc[r] = bj;
    for (int f = 0; f < FN; ++f) {
      float w = WihT[f * 1200 + j];
      float ev[16];
      const float* ep = &elds[f * 16];
#pragma unroll
      for (int r = 0; r < 4; ++r)
        *(float4*)(&ev[r * 4]) = *(const float4*)(ep + r * 4);
#pragma unroll
      for (int r = 0; r < 16; ++r) acc[r] = fmaf(ev[r], w, acc[r]);
    }
#pragma unroll
    for (int r = 0; r < 16; ++r) gx[(row0 + r) * 1200 + j] = acc[r];
  }
}

// ---------------------------------------------------------------------------
// K5a: h0 = user_emb[user_id]
// ---------------------------------------------------------------------------
__global__ void k5_init(const int* __restrict__ user_id,
                        const float* __restrict__ user_emb,
                        float* __restrict__ h0) {
  int idx = blockIdx.x * 256 + threadIdx.x;
  if (idx < BB * GG) {
    int b = idx / GG, g = idx - b * GG;
    h0[idx] = user_emb[(long)user_id[b] * GG + g];
  }
}

// ---------------------------------------------------------------------------
// K5b: one GRU step. grid = 32 batch-pairs x 8 g-chunks = 256 blocks.
// Block (bg, gc): batches {2bg, 2bg+1}, hidden units g in [gc*50, gc*50+50),
// i.e. the 150 gh outputs {gate*400 + gc*50 + gl}. Wpack makes those 150
// columns contiguous per g-row -> coalesced, independent loads.
// ---------------------------------------------------------------------------
__global__ __launch_bounds__(256) void k5_step(
    const float* __restrict__ h_prev,   // [64][400]
    float* __restrict__ h_next,         // [64][400]
    const float* __restrict__ Wpack,    // [8][400][150]
    const float* __restrict__ b_hh,     // [1200]
    const float* __restrict__ gx,       // [64][50][1200]
    const int* __restrict__ hist_len,   // [64]
    int step)
{
  const int gc = blockIdx.x & 7;
  const int bg = blockIdx.x >> 3;
  const int tid = threadIdx.x;
  __shared__ float hl[2][GG];
  __shared__ float ghl[2][3][50];

  for (int i = tid; i < 2 * GG; i += 256) {
    int b = i / GG, g = i - b * GG;
    hl[b][g] = h_prev[(2 * bg + b) * GG + g];
  }
  __syncthreads();

  float acc0 = 0.f, acc1 = 0.f;
  if (tid < 150) {
    const float* wp = Wpack + (size_t)gc * 400 * 150 + tid;
#pragma unroll 8
    for (int g = 0; g < GG; ++g) {
      float w = wp[g * 150];
      acc0 = fmaf(hl[0][g], w, acc0);
      acc1 = fmaf(hl[1][g], w, acc1);
    }
    int gate = tid / 50, gl = tid - gate * 50;
    float bb = b_hh[gate * 400 + gc * 50 + gl];
    ghl[0][gate][gl] = acc0 + bb;
    ghl[1][gate][gl] = acc1 + bb;
  }
  __syncthreads();

  if (tid < 100) {
    int b = tid / 50, gl = tid - (tid / 50) * 50;
    int babs = 2 * bg + b;
    int g = gc * 50 + gl;
    const float* gxp = gx + ((size_t)babs * NN + step) * 1200;
    float xr = gxp[g], xz = gxp[400 + g], xn = gxp[800 + g];
    float hr = ghl[b][0][gl], hz = ghl[b][1][gl], hn = ghl[b][2][gl];
    float r = 1.f / (1.f + __expf(-(xr + hr)));
    float z = 1.f / (1.f + __expf(-(xz + hz)));
    float nv = tanhf(xn + r * hn);
    float hold = hl[b][g];
    float hnew = (1.f - z) * nv + z * hold;
    h_next[babs * GG + g] = (step < hist_len[babs]) ? hnew : hold;
  }
}

// ---------------------------------------------------------------------------
// K5c: copy final h -> out
// ---------------------------------------------------------------------------
__global__ void k5_out(const float* __restrict__ h, float* __restrict__ out) {
  int idx = blockIdx.x * 256 + threadIdx.x;
  if (idx < BB * GG) out[idx] = h[idx];
}

// ---------------------------------------------------------------------------
extern "C" void kernel_launch(void* const* d_in, const int* in_sizes, int n_in,
                              void* d_out, int out_size, void* d_ws, size_t ws_size,
                              hipStream_t stream) {
  const int*   user_id   = (const int*)d_in[0];
  const int*   title     = (const int*)d_in[1];
  const int*   hist_len  = (const int*)d_in[2];
  const float* word_emb  = (const float*)d_in[3];
  const float* conv_w    = (const float*)d_in[4];
  const float* conv_b    = (const float*)d_in[5];
  const float* v         = (const float*)d_in[6];
  const float* vb        = (const float*)d_in[7];
  const float* q         = (const float*)d_in[8];
  const float* user_emb  = (const float*)d_in[9];
  const float* W_ih      = (const float*)d_in[10];
  const float* W_hh      = (const float*)d_in[11];
  const float* b_ih      = (const float*)d_in[12];
  const float* b_hh      = (const float*)d_in[13];
  float* out = (float*)d_out;

  char* ws = (char*)d_ws;
  size_t off = 0;
  auto take = [&](size_t bytes) {
    char* p = ws + off;
    off = (off + bytes + 255) & ~(size_t)255;
    return p;
  };
  __hip_bfloat16* C  = (__hip_bfloat16*)take((size_t)BB * NN * TT * FN * 2);  // 76.8MB
  float* score  = (float*)take((size_t)BB * NN * TT * 4);
  float* alpha  = (float*)take((size_t)BB * NN * TT * 4);
  float* e      = (float*)take((size_t)BB * NN * FN * 4);
  float* WihT   = (float*)take((size_t)1200 * 400 * 4);
  float* Wpack  = (float*)take((size_t)8 * 400 * 150 * 4);
  float* gx     = (float*)take((size_t)BB * NN * 1200 * 4);
  float* h0     = (float*)take((size_t)BB * GG * 4);
  float* h1     = (float*)take((size_t)BB * GG * 4);
  (void)ws_size;

  k_transpose<<<(1200 * 400 + 255) / 256, 256, 0, stream>>>(W_ih, WihT);
  k_pack_whh<<<(8 * 400 * 150 + 255) / 256, 256, 0, stream>>>(W_hh, Wpack);
  k1_conv_attn<<<BB * NN, 448, 0, stream>>>(title, word_emb, conv_w, conv_b, v,
                                            vb, q, C, score);
  k2_softmax_n<<<(BB * TT + 255) / 256, 256, 0, stream>>>(score, alpha);
  k3_wsum<<<BB * NN, 256, 0, stream>>>(alpha, C, e);
  k4_gx<<<BB * NN / 16, 256, 0, stream>>>(e, WihT, b_ih, gx);

  k5_init<<<(BB * GG + 255) / 256, 256, 0, stream>>>(user_id, user_emb, h0);
  float* hbuf[2] = {h0, h1};
  for (int step = 0; step < NN; ++step) {
    k5_step<<<256, 256, 0, stream>>>(hbuf[step & 1], hbuf[(step + 1) & 1],
                                     Wpack, b_hh, gx, hist_len, step);
  }
  k5_out<<<(BB * GG + 255) / 256, 256, 0, stream>>>(h0, out);
}

// Round 3
// 1274.503 us; speedup vs baseline: 10.0096x; 1.8904x over previous
//
#include <hip/hip_runtime.h>
#include <hip/hip_bf16.h>

#define BB 64
#define NN 50
#define TT 30
#define EE 300
#define FN 400
#define AA 200
#define GG 400

typedef __attribute__((ext_vector_type(8))) short bf16x8;
typedef __attribute__((ext_vector_type(4))) float f32x4;

// ---------------------------------------------------------------------------
// Prep kernels (one-time, tiny)
// ---------------------------------------------------------------------------
__global__ void k_transpose(const float* __restrict__ in, float* __restrict__ out) {
  int idx = blockIdx.x * 256 + threadIdx.x;
  if (idx < 1200 * 400) {
    int j = idx / 400, f = idx % 400;
    out[f * 1200 + j] = in[idx];
  }
}

__global__ void k_pack_whh(const float* __restrict__ Whh, float* __restrict__ Wpack) {
  int idx = blockIdx.x * 256 + threadIdx.x;
  if (idx < 8 * 400 * 150) {
    int jl = idx % 150;
    int g = (idx / 150) % 400;
    int gc = idx / (150 * 400);
    int gate = jl / 50, gl = jl - gate * 50;
    int j = gate * 400 + gc * 50 + gl;
    Wpack[idx] = Whh[j * 400 + g];
  }
}

// word_emb fp32 [50000][300] -> bf16 [50000][320] (zero pad cols 300..319)
__global__ void k_prep_emb(const float* __restrict__ w, __hip_bfloat16* __restrict__ o) {
  long i = (long)blockIdx.x * 256 + threadIdx.x;
  if (i < (long)50000 * 320) {
    int row = (int)(i / 320), c = (int)(i % 320);
    o[i] = __float2bfloat16(c < EE ? w[(long)row * EE + c] : 0.f);
  }
}

// conv_w fp32 [3][300][400] (k,e,f) -> WT bf16 [448 f][960 k] (zero padded)
__global__ void k_prep_wt(const float* __restrict__ cw, __hip_bfloat16* __restrict__ o) {
  int i = blockIdx.x * 256 + threadIdx.x;
  if (i < 448 * 960) {
    int f = i / 960, kk = i % 960;
    int ko = kk / 320, e = kk % 320;
    float val = (f < FN && e < EE) ? cw[(ko * EE + e) * FN + f] : 0.f;
    o[i] = __float2bfloat16(val);
  }
}

// v fp32 [400 f][200 a] -> vT bf16 [224 a][416 f] (zero padded)
__global__ void k_prep_v(const float* __restrict__ v, __hip_bfloat16* __restrict__ o) {
  int i = blockIdx.x * 256 + threadIdx.x;
  if (i < 224 * 416) {
    int a = i / 416, f = i % 416;
    o[i] = __float2bfloat16((a < AA && f < FN) ? v[f * AA + a] : 0.f);
  }
}

__global__ void k_prep_qvb(const float* __restrict__ q, const float* __restrict__ vb,
                           float* __restrict__ qp, float* __restrict__ vbp) {
  int i = threadIdx.x;
  if (i < 224) {
    qp[i]  = i < AA ? q[i]  : 0.f;
    vbp[i] = i < AA ? vb[i] : 0.f;
  }
}

// ---------------------------------------------------------------------------
// K_CONV: bf16 MFMA implicit-GEMM conv1d(K=3,pad=1) + bias + ReLU.
// Block = 4 titles: M=128 (4x32 rows, t in [0,32), only t<30 stored),
// N=448 (f, padded), K=960 (3 koff x 320 e).  8 waves: wm=wid>>2 (rows wm*64),
// wn=wid&3 (cols wn*112, 7 tiles).  acc 4x7 f32x4 = 112 VGPR.
// A-tile [128][32k] built per K-step from bf16 emb (im2col = shifted rows).
// B-tile [448][32k] staged from pre-transposed WT.  Rows padded to 40 ushorts
// (80B) -> 2-way-max bank aliasing on ds_read_b128 (free).
// ---------------------------------------------------------------------------
__global__ __launch_bounds__(512) void k_conv(
    const int* __restrict__ title, const __hip_bfloat16* __restrict__ emb,
    const __hip_bfloat16* __restrict__ WT, const float* __restrict__ conv_b,
    __hip_bfloat16* __restrict__ C)
{
  __shared__ __align__(16) ushort Alds[128 * 40];
  __shared__ __align__(16) ushort Blds[448 * 40];
  __shared__ int words[120];
  const int g = blockIdx.x;
  const int tid = threadIdx.x;
  const int lane = tid & 63;
  const int wid = tid >> 6;
  const int wm = wid >> 2;
  const int wn = wid & 3;
  const int l15 = lane & 15;
  const int l4 = lane >> 4;

  if (tid < 120) words[tid] = title[g * 120 + tid];

  f32x4 acc[4][7];
  {
    float bias[7];
#pragma unroll
    for (int nt = 0; nt < 7; ++nt) {
      int f = wn * 112 + nt * 16 + l15;
      bias[nt] = (f < FN) ? conv_b[f] : 0.f;
    }
#pragma unroll
    for (int mt = 0; mt < 4; ++mt)
#pragma unroll
      for (int nt = 0; nt < 7; ++nt) {
        acc[mt][nt][0] = bias[nt]; acc[mt][nt][1] = bias[nt];
        acc[mt][nt][2] = bias[nt]; acc[mt][nt][3] = bias[nt];
      }
  }
  __syncthreads();

  const int ar = tid >> 2, ac = tid & 3;   // A stage: row (0..127), 16B chunk
  const int ati = ar >> 5, at = ar & 31;

  for (int ko = 0; ko < 3; ++ko) {
    int w = at + ko - 1;
    const bool valid = (w >= 0 && w < TT);
    const ushort* asrc = valid ? (const ushort*)emb + (size_t)words[ati * 30 + w] * 320
                               : (const ushort*)emb;
    for (int ks = 0; ks < 10; ++ks) {
      uint4 av = make_uint4(0u, 0u, 0u, 0u);
      if (valid) av = *(const uint4*)(asrc + ks * 32 + ac * 8);
      *(uint4*)(&Alds[ar * 40 + ac * 8]) = av;
      for (int idx = tid; idx < 1792; idx += 512) {
        int f = idx >> 2, c = idx & 3;
        *(uint4*)(&Blds[f * 40 + c * 8]) =
            *(const uint4*)((const ushort*)WT + f * 960 + ko * 320 + ks * 32 + c * 8);
      }
      __syncthreads();
      bf16x8 af[4];
#pragma unroll
      for (int mt = 0; mt < 4; ++mt)
        af[mt] = *(const bf16x8*)(&Alds[(wm * 64 + mt * 16 + l15) * 40 + l4 * 8]);
#pragma unroll
      for (int nt = 0; nt < 7; ++nt) {
        bf16x8 bfr = *(const bf16x8*)(&Blds[(wn * 112 + nt * 16 + l15) * 40 + l4 * 8]);
#pragma unroll
        for (int mt = 0; mt < 4; ++mt)
          acc[mt][nt] = __builtin_amdgcn_mfma_f32_16x16x32_bf16(af[mt], bfr, acc[mt][nt], 0, 0, 0);
      }
      __syncthreads();
    }
  }

  // epilogue: ReLU + store C [96000][416] bf16 (rows t<30 only; f<416)
#pragma unroll
  for (int mt = 0; mt < 4; ++mt) {
    int rowb = wm * 64 + mt * 16 + l4 * 4;
    int ti = rowb >> 5;
    int tb = rowb & 31;
#pragma unroll
    for (int nt = 0; nt < 7; ++nt) {
      int f = wn * 112 + nt * 16 + l15;
      if (f < 416) {
#pragma unroll
        for (int r = 0; r < 4; ++r) {
          int t = tb + r;
          if (t < TT) {
            float vv = fmaxf(acc[mt][nt][r], 0.f);
            C[((size_t)(g * 4 + ti) * 30 + t) * 416 + f] = __float2bfloat16(vv);
          }
        }
      }
    }
  }
}

// ---------------------------------------------------------------------------
// K_ATTN: score[r] = sum_a tanh( (C[r,:] @ v[:,a]) + vb[a] ) * q[a]
// bf16 MFMA GEMM: M=96000 (375 blocks x 256 rows), N=224 (a, padded), K=416.
// 8 waves: wm=wid>>1 (rows wm*64, 4 Mtiles), wn=wid&1 (cols wn*112, 7 tiles).
// Epilogue in-register: tanh, *q, shfl_xor reduce over the 16-lane col group,
// LDS combine of the 2 n-waves.
// ---------------------------------------------------------------------------
__global__ __launch_bounds__(512) void k_attn(
    const __hip_bfloat16* __restrict__ C, const __hip_bfloat16* __restrict__ vT,
    const float* __restrict__ vbp, const float* __restrict__ qp,
    float* __restrict__ score)
{
  __shared__ __align__(16) ushort Clds[256 * 40];
  __shared__ __align__(16) ushort Vlds[224 * 40];
  __shared__ float sred[2][256];
  const int tid = threadIdx.x;
  const int lane = tid & 63, wid = tid >> 6;
  const int wm = wid >> 1, wn = wid & 1;
  const int l15 = lane & 15, l4 = lane >> 4;
  const size_t row0 = (size_t)blockIdx.x * 256;

  f32x4 acc[4][7];
  float ql[7];
#pragma unroll
  for (int nt = 0; nt < 7; ++nt) {
    int a = wn * 112 + nt * 16 + l15;
    ql[nt] = qp[a];
    float vbv = vbp[a];
#pragma unroll
    for (int mt = 0; mt < 4; ++mt) {
      acc[mt][nt][0] = vbv; acc[mt][nt][1] = vbv;
      acc[mt][nt][2] = vbv; acc[mt][nt][3] = vbv;
    }
  }

  for (int ks = 0; ks < 13; ++ks) {
    for (int idx = tid; idx < 1024; idx += 512) {
      int r = idx >> 2, c = idx & 3;
      *(uint4*)(&Clds[r * 40 + c * 8]) =
          *(const uint4*)((const ushort*)C + (row0 + r) * 416 + ks * 32 + c * 8);
    }
    for (int idx = tid; idx < 896; idx += 512) {
      int a = idx >> 2, c = idx & 3;
      *(uint4*)(&Vlds[a * 40 + c * 8]) =
          *(const uint4*)((const ushort*)vT + a * 416 + ks * 32 + c * 8);
    }
    __syncthreads();
    bf16x8 cf[4];
#pragma unroll
    for (int mt = 0; mt < 4; ++mt)
      cf[mt] = *(const bf16x8*)(&Clds[(wm * 64 + mt * 16 + l15) * 40 + l4 * 8]);
#pragma unroll
    for (int nt = 0; nt < 7; ++nt) {
      bf16x8 vf = *(const bf16x8*)(&Vlds[(wn * 112 + nt * 16 + l15) * 40 + l4 * 8]);
#pragma unroll
      for (int mt = 0; mt < 4; ++mt)
        acc[mt][nt] = __builtin_amdgcn_mfma_f32_16x16x32_bf16(cf[mt], vf, acc[mt][nt], 0, 0, 0);
    }
    __syncthreads();
  }

  float sums[4][4];
#pragma unroll
  for (int mt = 0; mt < 4; ++mt)
#pragma unroll
    for (int r = 0; r < 4; ++r) sums[mt][r] = 0.f;
#pragma unroll
  for (int mt = 0; mt < 4; ++mt)
#pragma unroll
    for (int nt = 0; nt < 7; ++nt)
#pragma unroll
      for (int r = 0; r < 4; ++r)
        sums[mt][r] += tanhf(acc[mt][nt][r]) * ql[nt];
#pragma unroll
  for (int mask = 1; mask < 16; mask <<= 1)
#pragma unroll
    for (int mt = 0; mt < 4; ++mt)
#pragma unroll
      for (int r = 0; r < 4; ++r)
        sums[mt][r] += __shfl_xor(sums[mt][r], mask);

  float outv = 0.f;
#pragma unroll
  for (int mt = 0; mt < 4; ++mt)
#pragma unroll
    for (int r = 0; r < 4; ++r)
      if (l15 == mt * 4 + r) outv = sums[mt][r];
  sred[wn][wm * 64 + (l15 >> 2) * 16 + l4 * 4 + (l15 & 3)] = outv;
  __syncthreads();
  if (tid < 256) score[row0 + tid] = sred[0][tid] + sred[1][tid];
}

// ---------------------------------------------------------------------------
// K2: softmax over the N (titles) axis, per (b,t).
// ---------------------------------------------------------------------------
__global__ void k2_softmax_n(const float* __restrict__ score, float* __restrict__ alpha) {
  int i = blockIdx.x * 256 + threadIdx.x;
  if (i >= BB * TT) return;
  int b = i / TT, t = i - b * TT;
  int base = b * (NN * TT) + t;
  float m = -1e30f;
  for (int n = 0; n < NN; ++n) m = fmaxf(m, score[base + n * TT]);
  float s = 0.f;
  for (int n = 0; n < NN; ++n) s += __expf(score[base + n * TT] - m);
  float inv = 1.f / s;
  for (int n = 0; n < NN; ++n)
    alpha[base + n * TT] = __expf(score[base + n * TT] - m) * inv;
}

// ---------------------------------------------------------------------------
// K3: e[bn,f] = sum_t alpha[bn,t] * C[bn,t,f]   (C stride 416)
// ---------------------------------------------------------------------------
__global__ __launch_bounds__(256) void k3_wsum(
    const float* __restrict__ alpha, const __hip_bfloat16* __restrict__ C,
    float* __restrict__ eout) {
  __shared__ float al[TT];
  const int bn = blockIdx.x;
  const int tid = threadIdx.x;
  if (tid < TT) al[tid] = alpha[bn * TT + tid];
  __syncthreads();
  for (int f = tid; f < FN; f += 256) {
    float s = 0.f;
#pragma unroll
    for (int t = 0; t < TT; ++t)
      s = fmaf(al[t], __bfloat162float(C[((size_t)bn * TT + t) * 416 + f]), s);
    eout[bn * FN + f] = s;
  }
}

// ---------------------------------------------------------------------------
// K4: gx = e @ W_ih^T + b_ih
// ---------------------------------------------------------------------------
__global__ __launch_bounds__(256) void k4_gx(
    const float* __restrict__ e, const float* __restrict__ WihT,
    const float* __restrict__ b_ih, float* __restrict__ gx) {
  __shared__ float elds[FN * 16];
  const int row0 = blockIdx.x * 16;
  const int tid = threadIdx.x;
  for (int idx = tid; idx < FN * 16; idx += 256) {
    int r = idx / FN, f = idx - r * FN;
    elds[f * 16 + r] = e[(row0 + r) * FN + f];
  }
  __syncthreads();
#pragma unroll
  for (int jc = 0; jc < 5; ++jc) {
    int j = tid + jc * 256;
    if (j >= 1200) break;
    float bj = b_ih[j];
    float acc[16];
#pragma unroll
    for (int r = 0; r < 16; ++r) acc[r] = bj;
    for (int f = 0; f < FN; ++f) {
      float w = WihT[f * 1200 + j];
      float ev[16];
      const float* ep = &elds[f * 16];
#pragma unroll
      for (int r = 0; r < 4; ++r)
        *(float4*)(&ev[r * 4]) = *(const float4*)(ep + r * 4);
#pragma unroll
      for (int r = 0; r < 16; ++r) acc[r] = fmaf(ev[r], w, acc[r]);
    }
#pragma unroll
    for (int r = 0; r < 16; ++r) gx[(row0 + r) * 1200 + j] = acc[r];
  }
}

// ---------------------------------------------------------------------------
// GRU
// ---------------------------------------------------------------------------
__global__ void k5_init(const int* __restrict__ user_id,
                        const float* __restrict__ user_emb,
                        float* __restrict__ h0) {
  int idx = blockIdx.x * 256 + threadIdx.x;
  if (idx < BB * GG) {
    int b = idx / GG, g = idx - b * GG;
    h0[idx] = user_emb[(long)user_id[b] * GG + g];
  }
}

__global__ __launch_bounds__(256) void k5_step(
    const float* __restrict__ h_prev, float* __restrict__ h_next,
    const float* __restrict__ Wpack, const float* __restrict__ b_hh,
    const float* __restrict__ gx, const int* __restrict__ hist_len, int step)
{
  const int gc = blockIdx.x & 7;
  const int bg = blockIdx.x >> 3;
  const int tid = threadIdx.x;
  __shared__ float hl[2][GG];
  __shared__ float ghl[2][3][50];

  for (int i = tid; i < 2 * GG; i += 256) {
    int b = i / GG, g = i - b * GG;
    hl[b][g] = h_prev[(2 * bg + b) * GG + g];
  }
  __syncthreads();

  float acc0 = 0.f, acc1 = 0.f;
  if (tid < 150) {
    const float* wp = Wpack + (size_t)gc * 400 * 150 + tid;
#pragma unroll 8
    for (int g = 0; g < GG; ++g) {
      float w = wp[g * 150];
      acc0 = fmaf(hl[0][g], w, acc0);
      acc1 = fmaf(hl[1][g], w, acc1);
    }
    int gate = tid / 50, gl = tid - gate * 50;
    float bb = b_hh[gate * 400 + gc * 50 + gl];
    ghl[0][gate][gl] = acc0 + bb;
    ghl[1][gate][gl] = acc1 + bb;
  }
  __syncthreads();

  if (tid < 100) {
    int b = tid / 50, gl = tid - (tid / 50) * 50;
    int babs = 2 * bg + b;
    int g = gc * 50 + gl;
    const float* gxp = gx + ((size_t)babs * NN + step) * 1200;
    float xr = gxp[g], xz = gxp[400 + g], xn = gxp[800 + g];
    float hr = ghl[b][0][gl], hz = ghl[b][1][gl], hn = ghl[b][2][gl];
    float r = 1.f / (1.f + __expf(-(xr + hr)));
    float z = 1.f / (1.f + __expf(-(xz + hz)));
    float nv = tanhf(xn + r * hn);
    float hold = hl[b][g];
    float hnew = (1.f - z) * nv + z * hold;
    h_next[babs * GG + g] = (step < hist_len[babs]) ? hnew : hold;
  }
}

__global__ void k5_out(const float* __restrict__ h, float* __restrict__ out) {
  int idx = blockIdx.x * 256 + threadIdx.x;
  if (idx < BB * GG) out[idx] = h[idx];
}

// ---------------------------------------------------------------------------
extern "C" void kernel_launch(void* const* d_in, const int* in_sizes, int n_in,
                              void* d_out, int out_size, void* d_ws, size_t ws_size,
                              hipStream_t stream) {
  const int*   user_id   = (const int*)d_in[0];
  const int*   title     = (const int*)d_in[1];
  const int*   hist_len  = (const int*)d_in[2];
  const float* word_emb  = (const float*)d_in[3];
  const float* conv_w    = (const float*)d_in[4];
  const float* conv_b    = (const float*)d_in[5];
  const float* v         = (const float*)d_in[6];
  const float* vb        = (const float*)d_in[7];
  const float* q         = (const float*)d_in[8];
  const float* user_emb  = (const float*)d_in[9];
  const float* W_ih      = (const float*)d_in[10];
  const float* W_hh      = (const float*)d_in[11];
  const float* b_ih      = (const float*)d_in[12];
  const float* b_hh      = (const float*)d_in[13];
  float* out = (float*)d_out;

  char* ws = (char*)d_ws;
  size_t off = 0;
  auto take = [&](size_t bytes) {
    char* p = ws + off;
    off = (off + bytes + 255) & ~(size_t)255;
    return p;
  };
  __hip_bfloat16* C      = (__hip_bfloat16*)take((size_t)BB * NN * TT * 416 * 2);  // 79.9MB
  float* score  = (float*)take((size_t)BB * NN * TT * 4);
  float* alpha  = (float*)take((size_t)BB * NN * TT * 4);
  float* e      = (float*)take((size_t)BB * NN * FN * 4);
  float* WihT   = (float*)take((size_t)1200 * 400 * 4);
  float* Wpack  = (float*)take((size_t)8 * 400 * 150 * 4);
  float* gx     = (float*)take((size_t)BB * NN * 1200 * 4);
  float* h0     = (float*)take((size_t)BB * GG * 4);
  float* h1     = (float*)take((size_t)BB * GG * 4);
  __hip_bfloat16* emb_bf = (__hip_bfloat16*)take((size_t)50000 * 320 * 2);        // 32MB
  __hip_bfloat16* WT     = (__hip_bfloat16*)take((size_t)448 * 960 * 2);
  __hip_bfloat16* vT     = (__hip_bfloat16*)take((size_t)224 * 416 * 2);
  float* qp     = (float*)take(224 * 4);
  float* vbp    = (float*)take(224 * 4);
  (void)ws_size;

  k_transpose<<<(1200 * 400 + 255) / 256, 256, 0, stream>>>(W_ih, WihT);
  k_pack_whh<<<(8 * 400 * 150 + 255) / 256, 256, 0, stream>>>(W_hh, Wpack);
  k_prep_emb<<<(50000 * 320 + 255) / 256, 256, 0, stream>>>(word_emb, emb_bf);
  k_prep_wt<<<(448 * 960 + 255) / 256, 256, 0, stream>>>(conv_w, WT);
  k_prep_v<<<(224 * 416 + 255) / 256, 256, 0, stream>>>(v, vT);
  k_prep_qvb<<<1, 256, 0, stream>>>(q, vb, qp, vbp);

  k_conv<<<BB * NN / 4, 512, 0, stream>>>(title, emb_bf, WT, conv_b, C);
  k_attn<<<BB * NN * TT / 256, 512, 0, stream>>>(C, vT, vbp, qp, score);
  k2_softmax_n<<<(BB * TT + 255) / 256, 256, 0, stream>>>(score, alpha);
  k3_wsum<<<BB * NN, 256, 0, stream>>>(alpha, C, e);
  k4_gx<<<BB * NN / 16, 256, 0, stream>>>(e, WihT, b_ih, gx);

  k5_init<<<(BB * GG + 255) / 256, 256, 0, stream>>>(user_id, user_emb, h0);
  float* hbuf[2] = {h0, h1};
  for (int step = 0; step < NN; ++step) {
    k5_step<<<256, 256, 0, stream>>>(hbuf[step & 1], hbuf[(step + 1) & 1],
                                     Wpack, b_hh, gx, hist_len, step);
  }
  k5_out<<<(BB * GG + 255) / 256, 256, 0, stream>>>(h0, out);
}